// Round 1
// baseline (447.430 us; speedup 1.0000x reference)
//
#include <hip/hip_runtime.h>
#include <cstdint>

// ---------------------------------------------------------------------------
// Fused SCAM kernel: one workgroup per (b,h) slice. 512 threads = 8 waves.
//  phase1: load x_l,x_h [64c][128w] -> LDS packed split-bf16 (hi|lo per u32)
//  stats : LN mean/rstd per w-row (over c)
//  phase2: q = LN1(xl)@Wq^T, k = LN2(xh)@Wk^T  (MFMA, split-bf16 x3)
//  phase3: S = q@k^T ; E = exp(S/8) -> LDS (reuses q/k space)
//  Z     : row sums (attn_h denom) and col sums (attn_l denom) of E
//  PV    : O_h = E@xh, O_l = E^T@xl ; normalize rows by 1/Z -> LDS (reuses E)
//  phase7: out_l = xl + O_h@Wv2^T ; out_h = xh + O_l@Wv1^T  -> global
// ---------------------------------------------------------------------------

#define XPAD 132   // row stride (w) of packed X tiles
#define QPAD 68    // row stride of q/k/O (f32)
#define EPAD 132   // row stride of E (f32)

typedef __attribute__((ext_vector_type(8))) short bf16x8;
typedef __attribute__((ext_vector_type(4))) float f32x4;
typedef __attribute__((ext_vector_type(4))) unsigned u32x4;

__device__ __forceinline__ unsigned bf16_rne(float x) {
  unsigned u = __float_as_uint(x);
  return (u + 0x7FFFu + ((u >> 16) & 1u)) >> 16;
}
// pack f32 -> (bf16_hi << 16) | bf16_lo, with lo = rne(x - hi)
__device__ __forceinline__ unsigned split_pack(float x) {
  unsigned h = bf16_rne(x);
  float hr = __uint_as_float(h << 16);
  unsigned l = bf16_rne(x - hr);
  return (h << 16) | l;
}
__device__ __forceinline__ float unpack_f(unsigned p) {
  return __uint_as_float(p & 0xFFFF0000u) + __uint_as_float(p << 16);
}
__device__ __forceinline__ void split_frag8(const float v[8], bf16x8& fh, bf16x8& fl) {
#pragma unroll
  for (int j = 0; j < 8; ++j) {
    unsigned hb = bf16_rne(v[j]);
    float hr = __uint_as_float(hb << 16);
    unsigned lb = bf16_rne(v[j] - hr);
    fh[j] = (short)hb;
    fl[j] = (short)lb;
  }
}
__device__ __forceinline__ void ld8(const float* p, float v[8]) {
  f32x4 a0 = *(const f32x4*)p;
  f32x4 a1 = *(const f32x4*)(p + 4);
  v[0] = a0[0]; v[1] = a0[1]; v[2] = a0[2]; v[3] = a0[3];
  v[4] = a1[0]; v[5] = a1[1]; v[6] = a1[2]; v[7] = a1[3];
}
// D += (Ah+Al)@(Bh+Bl) dropping Al@Bl  (~2^-17 rel error)
__device__ __forceinline__ f32x4 mm3(bf16x8 ah, bf16x8 al, bf16x8 bh, bf16x8 bl, f32x4 c) {
  c = __builtin_amdgcn_mfma_f32_16x16x32_bf16(al, bh, c, 0, 0, 0);
  c = __builtin_amdgcn_mfma_f32_16x16x32_bf16(ah, bl, c, 0, 0, 0);
  c = __builtin_amdgcn_mfma_f32_16x16x32_bf16(ah, bh, c, 0, 0, 0);
  return c;
}

__launch_bounds__(512, 1)
__global__ void scam_fused(const float* __restrict__ xl_g, const float* __restrict__ xh_g,
                           const float* __restrict__ ln1g, const float* __restrict__ ln1b,
                           const float* __restrict__ ln2g, const float* __restrict__ ln2b,
                           const float* __restrict__ Wq, const float* __restrict__ Wk,
                           const float* __restrict__ Wv1, const float* __restrict__ Wv2,
                           float* __restrict__ out) {
  // 138 KiB static LDS -> 1 block/CU
  __shared__ __align__(16) unsigned Xb[2][64][XPAD];   // packed split-bf16, [mat][c][w]
  __shared__ __align__(16) float R1[17408];            // q|k -> E -> O_h|O_l
  __shared__ float meanv[2][128], rstdv[2][128];
  __shared__ float zri[128], zci[128];
  __shared__ float gbv[4][64];                         // ln1g, ln1b, ln2g, ln2b

  const int tid = threadIdx.x;
  const int lane = tid & 63;
  const int wid = tid >> 6;   // 0..7 (one 16-row m-tile per wave)
  const int l15 = lane & 15;
  const int lg = lane >> 4;   // 0..3
  const int s = blockIdx.x;
  const int b = s >> 7, h = s & 127;
  const size_t xoff = (size_t)b * 1048576u + (size_t)h * 128u;

  // ---- phase 0: gamma/beta to LDS ----
  if (tid < 256) {
    int g = tid >> 6, e = tid & 63;
    const float* src = (g == 0) ? ln1g : ((g == 1) ? ln1b : ((g == 2) ? ln2g : ln2b));
    gbv[g][e] = src[e];
  }

  // ---- phase 1: load X tiles, split-pack into LDS ----
  {
    const int f4 = tid & 31;   // w-quad index (coalesced within wave)
    const int c2 = tid >> 5;   // 0..15
#pragma unroll
    for (int mat = 0; mat < 2; ++mat) {
      const float* xg = mat ? xh_g : xl_g;
#pragma unroll
      for (int i = 0; i < 4; ++i) {
        int c = c2 * 4 + i;
        f32x4 v = *(const f32x4*)(xg + xoff + (size_t)c * 16384u + f4 * 4);
        u32x4 pk;
#pragma unroll
        for (int j = 0; j < 4; ++j) pk[j] = split_pack(v[j]);
        *(u32x4*)&Xb[mat][c][f4 * 4] = pk;
      }
    }
  }
  __syncthreads();

  // ---- LN stats: one thread per (mat, w) row ----
  if (tid < 256) {
    int mat = tid >> 7, w = tid & 127;
    float s1 = 0.f, s2 = 0.f;
#pragma unroll 8
    for (int c = 0; c < 64; ++c) {
      float x = unpack_f(Xb[mat][c][w]);
      s1 += x;
      s2 += x * x;
    }
    float mn = s1 * (1.0f / 64.0f);
    float var = fmaxf(s2 * (1.0f / 64.0f) - mn * mn, 0.0f);
    meanv[mat][w] = mn;
    rstdv[mat][w] = rsqrtf(var + 1e-5f);
  }
  __syncthreads();

  // ---- phase 2: q/k projections ----
  {
#pragma unroll
    for (int mat = 0; mat < 2; ++mat) {
      bf16x8 Ah[2], Al[2];
      {
        int w = wid * 16 + l15;
        float mn = meanv[mat][w], rs = rstdv[mat][w];
#pragma unroll
        for (int ks = 0; ks < 2; ++ks) {
          int c0 = ks * 32 + lg * 8;
          float v[8];
#pragma unroll
          for (int j = 0; j < 8; ++j) {
            float x = unpack_f(Xb[mat][c0 + j][w]);
            v[j] = (x - mn) * rs * gbv[mat * 2][c0 + j] + gbv[mat * 2 + 1][c0 + j];
          }
          split_frag8(v, Ah[ks], Al[ks]);
        }
      }
      const float* W = mat ? Wk : Wq;
      f32x4 acc[4];
#pragma unroll
      for (int nt = 0; nt < 4; ++nt)
#pragma unroll
        for (int r = 0; r < 4; ++r) acc[nt][r] = 0.f;
#pragma unroll
      for (int nt = 0; nt < 4; ++nt) {
#pragma unroll
        for (int ks = 0; ks < 2; ++ks) {
          int co = nt * 16 + l15;
          float v[8];
          ld8(W + co * 64 + ks * 32 + lg * 8, v);
          bf16x8 Bh, Bl;
          split_frag8(v, Bh, Bl);
          acc[nt] = mm3(Ah[ks], Al[ks], Bh, Bl, acc[nt]);
        }
      }
      float* dst = mat ? (R1 + 8704) : R1;   // q at 0, k at 8704
      int row0 = wid * 16 + lg * 4;
#pragma unroll
      for (int nt = 0; nt < 4; ++nt) {
        int col = nt * 16 + l15;
#pragma unroll
        for (int r = 0; r < 4; ++r) dst[(row0 + r) * QPAD + col] = acc[nt][r];
      }
    }
  }
  __syncthreads();

  // ---- phase 3: S = q@k^T, then E = exp(S/8) over q/k space ----
  {
    bf16x8 Ah[2], Al[2];
    {
      int w = wid * 16 + l15;
#pragma unroll
      for (int ks = 0; ks < 2; ++ks) {
        float v[8];
        ld8(R1 + w * QPAD + ks * 32 + lg * 8, v);
        split_frag8(v, Ah[ks], Al[ks]);
      }
    }
    f32x4 acc[8];
#pragma unroll
    for (int nt = 0; nt < 8; ++nt)
#pragma unroll
      for (int r = 0; r < 4; ++r) acc[nt][r] = 0.f;
#pragma unroll
    for (int nt = 0; nt < 8; ++nt) {
#pragma unroll
      for (int ks = 0; ks < 2; ++ks) {
        int wk = nt * 16 + l15;
        float v[8];
        ld8(R1 + 8704 + wk * QPAD + ks * 32 + lg * 8, v);
        bf16x8 Bh, Bl;
        split_frag8(v, Bh, Bl);
        acc[nt] = mm3(Ah[ks], Al[ks], Bh, Bl, acc[nt]);
      }
    }
    __syncthreads();   // all q/k reads done before E overwrites
    int row0 = wid * 16 + lg * 4;
#pragma unroll
    for (int nt = 0; nt < 8; ++nt) {
      int col = nt * 16 + l15;
#pragma unroll
      for (int r = 0; r < 4; ++r) {
        // exp(S/sqrt(64)) = exp2(S * log2(e)/8); |S|<~6 so no max-subtraction needed
        R1[(row0 + r) * EPAD + col] =
            __builtin_amdgcn_exp2f(acc[nt][r] * 0.18033688011112042f);
      }
    }
  }
  __syncthreads();

  // ---- Z: row sums (Zr) and column sums (Zc) of E ----
  if (tid < 256) {
    int mode = tid >> 7, idx = tid & 127;
    float sum = 0.f;
    if (mode == 0) {
#pragma unroll 4
      for (int j4 = 0; j4 < 32; ++j4) {
        f32x4 e = *(const f32x4*)(R1 + idx * EPAD + j4 * 4);
        sum += (e[0] + e[1]) + (e[2] + e[3]);
      }
      zri[idx] = 1.0f / sum;
    } else {
#pragma unroll 8
      for (int i = 0; i < 128; ++i) sum += R1[i * EPAD + idx];
      zci[idx] = 1.0f / sum;
    }
  }

  // ---- PV: O_h = E@Xh (side0), O_l = E^T@Xl (side1) ----
  {
    f32x4 acc[2][4];
#pragma unroll
    for (int sd = 0; sd < 2; ++sd)
#pragma unroll
      for (int nt = 0; nt < 4; ++nt)
#pragma unroll
        for (int r = 0; r < 4; ++r) acc[sd][nt][r] = 0.f;
#pragma unroll
    for (int side = 0; side < 2; ++side) {
      const unsigned(*X)[XPAD] = Xb[side ? 0 : 1];   // side0 reads xh, side1 reads xl
#pragma unroll
      for (int kt = 0; kt < 4; ++kt) {
        bf16x8 Ah, Al;
        {
          int rowc = wid * 16 + l15;
          float v[8];
          if (side == 0) {
            ld8(R1 + rowc * EPAD + kt * 32 + lg * 8, v);   // E rows
          } else {
            int k0 = kt * 32 + lg * 8;
#pragma unroll
            for (int j = 0; j < 8; ++j) v[j] = R1[(k0 + j) * EPAD + rowc];  // E cols
          }
          split_frag8(v, Ah, Al);
        }
#pragma unroll
        for (int nt = 0; nt < 4; ++nt) {
          int c = nt * 16 + l15;
          const unsigned* p = &X[c][kt * 32 + lg * 8];
          u32x4 p0 = *(const u32x4*)p;
          u32x4 p1 = *(const u32x4*)(p + 4);
          bf16x8 Bh, Bl;
#pragma unroll
          for (int j = 0; j < 4; ++j) {
            Bh[j] = (short)(p0[j] >> 16);
            Bl[j] = (short)(p0[j] & 0xFFFFu);
            Bh[j + 4] = (short)(p1[j] >> 16);
            Bl[j + 4] = (short)(p1[j] & 0xFFFFu);
          }
          acc[side][nt] = mm3(Ah, Al, Bh, Bl, acc[side][nt]);
        }
      }
    }
    __syncthreads();   // E reads done; zri/zci now visible
    int row0 = wid * 16 + lg * 4;
#pragma unroll
    for (int side = 0; side < 2; ++side) {
      float* dst = side ? (R1 + 8704) : R1;   // O_h at 0, O_l at 8704
#pragma unroll
      for (int nt = 0; nt < 4; ++nt) {
        int col = nt * 16 + l15;
#pragma unroll
        for (int r = 0; r < 4; ++r) {
          float zs = side ? zci[row0 + r] : zri[row0 + r];
          dst[(row0 + r) * QPAD + col] = acc[side][nt][r] * zs;
        }
      }
    }
  }
  __syncthreads();

  // ---- phase 7: out_l = Xl + O_h@Wv2^T ; out_h = Xh + O_l@Wv1^T ----
  {
#pragma unroll
    for (int oi = 0; oi < 2; ++oi) {
      const float* Osrc = oi ? (R1 + 8704) : R1;
      const float* W = oi ? Wv1 : Wv2;
      bf16x8 Ah[2], Al[2];
      {
        int w = wid * 16 + l15;
#pragma unroll
        for (int ks = 0; ks < 2; ++ks) {
          float v[8];
          ld8(Osrc + w * QPAD + ks * 32 + lg * 8, v);
          split_frag8(v, Ah[ks], Al[ks]);
        }
      }
      f32x4 acc[4];
#pragma unroll
      for (int nt = 0; nt < 4; ++nt)
#pragma unroll
        for (int r = 0; r < 4; ++r) acc[nt][r] = 0.f;
#pragma unroll
      for (int nt = 0; nt < 4; ++nt) {
#pragma unroll
        for (int ks = 0; ks < 2; ++ks) {
          int co = nt * 16 + l15;
          float v[8];
          ld8(W + co * 64 + ks * 32 + lg * 8, v);
          bf16x8 Bh, Bl;
          split_frag8(v, Bh, Bl);
          acc[nt] = mm3(Ah[ks], Al[ks], Bh, Bl, acc[nt]);
        }
      }
      const unsigned(*Xr)[XPAD] = Xb[oi];   // oi0 residual xl, oi1 residual xh
      float* og = out + (size_t)oi * 16777216u + xoff;
      int w0 = wid * 16 + lg * 4;
#pragma unroll
      for (int nt = 0; nt < 4; ++nt) {
        int c = nt * 16 + l15;
        u32x4 pr = *(const u32x4*)&Xr[c][w0];
        f32x4 o;
#pragma unroll
        for (int r = 0; r < 4; ++r) o[r] = unpack_f(pr[r]) + acc[nt][r];
        *(f32x4*)(og + (size_t)c * 16384u + w0) = o;
      }
    }
  }
}

extern "C" void kernel_launch(void* const* d_in, const int* in_sizes, int n_in,
                              void* d_out, int out_size, void* d_ws, size_t ws_size,
                              hipStream_t stream) {
  (void)in_sizes; (void)n_in; (void)d_ws; (void)ws_size; (void)out_size;
  scam_fused<<<2048, 512, 0, stream>>>(
      (const float*)d_in[0], (const float*)d_in[1],
      (const float*)d_in[2], (const float*)d_in[3],
      (const float*)d_in[4], (const float*)d_in[5],
      (const float*)d_in[6], (const float*)d_in[7],
      (const float*)d_in[8], (const float*)d_in[9],
      (float*)d_out);
}

// Round 2
// 366.855 us; speedup vs baseline: 1.2196x; 1.2196x over previous
//
#include <hip/hip_runtime.h>
#include <cstdint>

// ---------------------------------------------------------------------------
// SCAM fused, v2.
//  - scam_prepack: folds LN gamma into Wq/Wk, splits all W into hi/lo bf16
//    planes laid out in MFMA B-fragment order (d_ws), computes sq/bq/sk/bk.
//  - scam_main: 1024 thr (16 waves, 8 row-stripes x 2 col-halves), LDS planes:
//    X hi/lo -> LN stats -> q/k proj (LN folded into epilogue) -> S=q@k^T ->
//    E=exp(S/8) packed -> row/col sums -> O_h=E@Xh, O_l=E^T@Xl -> +W_v proj
//    with residual -> out. All MFMA inputs are split-bf16 (3-MFMA scheme).
// ---------------------------------------------------------------------------

typedef __attribute__((ext_vector_type(8))) short bf16x8;
typedef __attribute__((ext_vector_type(4))) float f32x4;
typedef __attribute__((ext_vector_type(4))) unsigned u32x4;
typedef __attribute__((ext_vector_type(4))) unsigned short u16x4;

#define W2 136   // X plane row stride (ushort), 272 B: 16B-aligned rows, 2-way banks
#define QP 72    // q/k plane row stride (ushort), 144 B
#define EP 132   // E row stride (u32), 528 B
#define OP 68    // O row stride (u32), 272 B

__device__ __forceinline__ unsigned rne_hi(float x) {
  unsigned u = __float_as_uint(x);
  return (u + 0x7FFFu + ((u >> 16) & 1u)) >> 16;
}
__device__ __forceinline__ void split2(float x, unsigned short& h, unsigned short& l) {
  unsigned hb = rne_hi(x);
  float rf = x - __uint_as_float(hb << 16);
  h = (unsigned short)hb;
  l = (unsigned short)(__float_as_uint(rf) >> 16);   // trunc lo: err < 2^-17 rel
}
__device__ __forceinline__ unsigned split_pack(float x) {
  unsigned short h, l; split2(x, h, l);
  return ((unsigned)h << 16) | (unsigned)l;
}
__device__ __forceinline__ float comb(unsigned h, unsigned l) {
  return __uint_as_float(h << 16) + __uint_as_float(l << 16);
}
__device__ __forceinline__ float unpack_f(unsigned p) {
  return __uint_as_float(p & 0xFFFF0000u) + __uint_as_float(p << 16);
}
__device__ __forceinline__ f32x4 mm3(bf16x8 ah, bf16x8 al, bf16x8 bh, bf16x8 bl, f32x4 c) {
  c = __builtin_amdgcn_mfma_f32_16x16x32_bf16(al, bh, c, 0, 0, 0);
  c = __builtin_amdgcn_mfma_f32_16x16x32_bf16(ah, bl, c, 0, 0, 0);
  c = __builtin_amdgcn_mfma_f32_16x16x32_bf16(ah, bh, c, 0, 0, 0);
  return c;
}

// WP layout (ushort): [mat 0..3][plane hi/lo][ntks 0..7][lane 0..63][j 0..7]
// mat: 0=g1*Wq, 1=g2*Wk, 2=Wv1, 3=Wv2. vecs f32[256] = sq|bq|sk|bk.
__global__ void scam_prepack(const float* __restrict__ ln1g, const float* __restrict__ ln1b,
                             const float* __restrict__ ln2g, const float* __restrict__ ln2b,
                             const float* __restrict__ Wq, const float* __restrict__ Wk,
                             const float* __restrict__ Wv1, const float* __restrict__ Wv2,
                             unsigned short* __restrict__ WP, float* __restrict__ vecs) {
  int t = blockIdx.x * 256 + threadIdx.x;           // 16384 threads, one per element
  int mat = t >> 12, rem = t & 4095, co = rem >> 6, c = rem & 63;
  const float* Ws = (mat == 0) ? Wq : (mat == 1) ? Wk : (mat == 2) ? Wv1 : Wv2;
  float g = 1.0f;
  if (mat == 0) g = ln1g[c];
  else if (mat == 1) g = ln2g[c];
  float val = Ws[co * 64 + c] * g;
  unsigned short h, l; split2(val, h, l);
  int nt = co >> 4, l15 = co & 15, ks = c >> 5, lg = (c >> 3) & 3, j = c & 7;
  int lanei = lg * 16 + l15;
  int ntk = nt * 2 + ks;
  WP[((mat * 2 + 0) * 8 + ntk) * 512 + lanei * 8 + j] = h;
  WP[((mat * 2 + 1) * 8 + ntk) * 512 + lanei * 8 + j] = l;
  if (blockIdx.x == 0 && threadIdx.x < 256) {
    int which = threadIdx.x >> 6, o = threadIdx.x & 63;
    const float* Wm = (which < 2) ? Wq : Wk;
    const float* gv = (which == 0) ? ln1g : (which == 1) ? ln1b : (which == 2) ? ln2g : ln2b;
    float ssum = 0.f;
    for (int cc = 0; cc < 64; ++cc) ssum += gv[cc] * Wm[o * 64 + cc];
    vecs[which * 64 + o] = ssum;
  }
}

struct SMem {
  unsigned short Xhi[2][64][W2];
  unsigned short Xlo[2][64][W2];
  union {
    unsigned short QK[4][128][QP];   // 0=qhi 1=qlo 2=khi 3=klo
    unsigned Epk[128][EP];
    unsigned Opk[2][128][OP];        // 0=O_h 1=O_l (packed hi|lo)
  } rb;
  float meanv[2][128];
  float rstdv[2][128];
  float zr[128];
  float zc[128];
};

__launch_bounds__(1024, 1)
__global__ void scam_main(const float* __restrict__ xl_g, const float* __restrict__ xh_g,
                          const unsigned short* __restrict__ WP, const float* __restrict__ vecs,
                          float* __restrict__ out) {
  __shared__ __align__(16) SMem sm;
  const int tid = threadIdx.x;
  const int lane = tid & 63;
  const int wid = tid >> 6;       // 0..15
  const int stripe = wid >> 1;    // row-stripe 0..7 (16 rows each)
  const int chalf = wid & 1;      // column half
  const int l15 = lane & 15;
  const int lg = lane >> 4;
  const int s = blockIdx.x;
  const size_t xoff = (size_t)(s >> 7) * 1048576u + (size_t)(s & 127) * 128u;

  // ---- phase 1: global -> X hi/lo planes ----
  {
    int c0 = tid >> 5, q4 = tid & 31;
#pragma unroll
    for (int mat = 0; mat < 2; ++mat) {
      const float* xg = mat ? xh_g : xl_g;
#pragma unroll
      for (int half = 0; half < 2; ++half) {
        int c = c0 + half * 32;
        f32x4 v = *(const f32x4*)(xg + xoff + (size_t)c * 16384u + q4 * 4);
        u16x4 h4, l4;
#pragma unroll
        for (int j = 0; j < 4; ++j) { unsigned short hh, ll; split2(v[j], hh, ll); h4[j] = hh; l4[j] = ll; }
        *(u16x4*)&sm.Xhi[mat][c][q4 * 4] = h4;
        *(u16x4*)&sm.Xlo[mat][c][q4 * 4] = l4;
      }
    }
  }
  __syncthreads();

  // ---- LN stats: 4 threads per (mat,w) row ----
  {
    int row = tid >> 2, qu = tid & 3;
    int mat = row >> 7, w = row & 127;
    float s1 = 0.f, s2 = 0.f;
#pragma unroll
    for (int i = 0; i < 16; ++i) {
      int c = qu * 16 + i;
      float x = comb(sm.Xhi[mat][c][w], sm.Xlo[mat][c][w]);
      s1 += x; s2 += x * x;
    }
    s1 += __shfl_xor(s1, 1); s2 += __shfl_xor(s2, 1);
    s1 += __shfl_xor(s1, 2); s2 += __shfl_xor(s2, 2);
    if (qu == 0) {
      float mn = s1 * (1.f / 64.f);
      float var = fmaxf(s2 * (1.f / 64.f) - mn * mn, 0.f);
      sm.meanv[mat][w] = mn;
      sm.rstdv[mat][w] = rsqrtf(var + 1e-5f);
    }
  }
  __syncthreads();

  // ---- phase 2: q/k = rs*(x@W'^T - mn*sv) + bv -> q/k planes ----
  {
    const int w = stripe * 16 + l15;
#pragma unroll
    for (int mat = 0; mat < 2; ++mat) {
      bf16x8 Ah[2], Al[2];
#pragma unroll
      for (int ks = 0; ks < 2; ++ks)
#pragma unroll
        for (int j = 0; j < 8; ++j) {
          int c = ks * 32 + lg * 8 + j;
          Ah[ks][j] = (short)sm.Xhi[mat][c][w];
          Al[ks][j] = (short)sm.Xlo[mat][c][w];
        }
      f32x4 acc[2];
#pragma unroll
      for (int nt = 0; nt < 2; ++nt)
#pragma unroll
        for (int r = 0; r < 4; ++r) acc[nt][r] = 0.f;
#pragma unroll
      for (int nt = 0; nt < 2; ++nt) {
        int ntg = chalf * 2 + nt;
#pragma unroll
        for (int ks = 0; ks < 2; ++ks) {
          const unsigned short* wp = WP + ((mat * 2 + 0) * 8 + (ntg * 2 + ks)) * 512 + lane * 8;
          bf16x8 Bh = *(const bf16x8*)wp;
          bf16x8 Bl = *(const bf16x8*)(wp + 4096);
          acc[nt] = mm3(Ah[ks], Al[ks], Bh, Bl, acc[nt]);
        }
      }
#pragma unroll
      for (int nt = 0; nt < 2; ++nt) {
        int co = (chalf * 2 + nt) * 16 + l15;
        float sv = vecs[mat * 128 + co];
        float bv = vecs[mat * 128 + 64 + co];
#pragma unroll
        for (int r = 0; r < 4; ++r) {
          int wr = stripe * 16 + lg * 4 + r;
          float qv = sm.rstdv[mat][wr] * (acc[nt][r] - sm.meanv[mat][wr] * sv) + bv;
          unsigned short hh, ll; split2(qv, hh, ll);
          sm.rb.QK[mat * 2 + 0][wr][co] = hh;
          sm.rb.QK[mat * 2 + 1][wr][co] = ll;
        }
      }
    }
  }
  __syncthreads();

  // ---- phase 3: S = q@k^T ; E = exp(S/8) packed (overwrites q/k after sync) ----
  {
    const int w = stripe * 16 + l15;
    bf16x8 Ah[2], Al[2];
#pragma unroll
    for (int ks = 0; ks < 2; ++ks) {
      Ah[ks] = *(const bf16x8*)&sm.rb.QK[0][w][ks * 32 + lg * 8];
      Al[ks] = *(const bf16x8*)&sm.rb.QK[1][w][ks * 32 + lg * 8];
    }
    f32x4 acc[4];
#pragma unroll
    for (int nt = 0; nt < 4; ++nt)
#pragma unroll
      for (int r = 0; r < 4; ++r) acc[nt][r] = 0.f;
#pragma unroll
    for (int nt = 0; nt < 4; ++nt) {
      int kw = (chalf * 4 + nt) * 16 + l15;
#pragma unroll
      for (int ks = 0; ks < 2; ++ks) {
        bf16x8 Bh = *(const bf16x8*)&sm.rb.QK[2][kw][ks * 32 + lg * 8];
        bf16x8 Bl = *(const bf16x8*)&sm.rb.QK[3][kw][ks * 32 + lg * 8];
        acc[nt] = mm3(Ah[ks], Al[ks], Bh, Bl, acc[nt]);
      }
    }
    __syncthreads();   // all q/k reads complete before E overwrites
#pragma unroll
    for (int nt = 0; nt < 4; ++nt) {
      int col = (chalf * 4 + nt) * 16 + l15;
#pragma unroll
      for (int r = 0; r < 4; ++r) {
        int row = stripe * 16 + lg * 4 + r;
        float e = __builtin_amdgcn_exp2f(acc[nt][r] * 0.18033688011112042f);
        sm.rb.Epk[row][col] = split_pack(e);
      }
    }
  }
  __syncthreads();

  // ---- Z: row sums (zr) / col sums (zc) of E ----
  {
    int qu = tid & 3;
    float sum = 0.f;
    if (tid < 512) {
      int row = tid >> 2;
#pragma unroll
      for (int i = 0; i < 8; ++i) {
        u32x4 p = *(const u32x4*)&sm.rb.Epk[row][qu * 32 + i * 4];
#pragma unroll
        for (int j = 0; j < 4; ++j) sum += unpack_f(p[j]);
      }
      sum += __shfl_xor(sum, 1);
      sum += __shfl_xor(sum, 2);
      if (qu == 0) sm.zr[row] = 1.0f / sum;
    } else {
      int col = (tid >> 2) & 127;
#pragma unroll 8
      for (int i = 0; i < 32; ++i) sum += unpack_f(sm.rb.Epk[qu * 32 + i][col]);
      sum += __shfl_xor(sum, 1);
      sum += __shfl_xor(sum, 2);
      if (qu == 0) sm.zc[col] = 1.0f / sum;
    }
  }
  __syncthreads();

  // ---- PV: O_h = E@Xh, O_l = E^T@Xl -> Opk (overwrites E after sync) ----
  {
    f32x4 acc0[2], acc1[2];
#pragma unroll
    for (int nt = 0; nt < 2; ++nt)
#pragma unroll
      for (int r = 0; r < 4; ++r) { acc0[nt][r] = 0.f; acc1[nt][r] = 0.f; }
#pragma unroll
    for (int kt = 0; kt < 4; ++kt) {
      // side0 A: E rows
      {
        int row = stripe * 16 + l15;
        u32x4 p0 = *(const u32x4*)&sm.rb.Epk[row][kt * 32 + lg * 8];
        u32x4 p1 = *(const u32x4*)&sm.rb.Epk[row][kt * 32 + lg * 8 + 4];
        bf16x8 Ah, Al;
#pragma unroll
        for (int j = 0; j < 4; ++j) {
          Ah[j] = (short)(p0[j] >> 16);     Al[j] = (short)(p0[j] & 0xFFFFu);
          Ah[j + 4] = (short)(p1[j] >> 16); Al[j + 4] = (short)(p1[j] & 0xFFFFu);
        }
#pragma unroll
        for (int nt = 0; nt < 2; ++nt) {
          int c = (chalf * 2 + nt) * 16 + l15;
          bf16x8 Bh = *(const bf16x8*)&sm.Xhi[1][c][kt * 32 + lg * 8];
          bf16x8 Bl = *(const bf16x8*)&sm.Xlo[1][c][kt * 32 + lg * 8];
          acc0[nt] = mm3(Ah, Al, Bh, Bl, acc0[nt]);
        }
      }
      // side1 A: E columns (gather)
      {
        bf16x8 Gh, Gl;
#pragma unroll
        for (int j = 0; j < 8; ++j) {
          unsigned p = sm.rb.Epk[kt * 32 + lg * 8 + j][stripe * 16 + l15];
          Gh[j] = (short)(p >> 16); Gl[j] = (short)(p & 0xFFFFu);
        }
#pragma unroll
        for (int nt = 0; nt < 2; ++nt) {
          int c = (chalf * 2 + nt) * 16 + l15;
          bf16x8 Bh = *(const bf16x8*)&sm.Xhi[0][c][kt * 32 + lg * 8];
          bf16x8 Bl = *(const bf16x8*)&sm.Xlo[0][c][kt * 32 + lg * 8];
          acc1[nt] = mm3(Gh, Gl, Bh, Bl, acc1[nt]);
        }
      }
    }
    __syncthreads();   // all E reads complete before O overwrites
#pragma unroll
    for (int nt = 0; nt < 2; ++nt) {
      int col = (chalf * 2 + nt) * 16 + l15;
#pragma unroll
      for (int r = 0; r < 4; ++r) {
        int row = stripe * 16 + lg * 4 + r;
        sm.rb.Opk[0][row][col] = split_pack(acc0[nt][r] * sm.zr[row]);
        sm.rb.Opk[1][row][col] = split_pack(acc1[nt][r] * sm.zc[row]);
      }
    }
  }
  __syncthreads();

  // ---- phase 7: out_l = xl + O_h@Wv2^T ; out_h = xh + O_l@Wv1^T ----
#pragma unroll
  for (int oi = 0; oi < 2; ++oi) {
    const int wm = oi ? 2 : 3;   // oi0 -> Wv2 (mat3), oi1 -> Wv1 (mat2)
    const int w = stripe * 16 + l15;
    bf16x8 Ah[2], Al[2];
#pragma unroll
    for (int ks = 0; ks < 2; ++ks) {
      u32x4 p0 = *(const u32x4*)&sm.rb.Opk[oi][w][ks * 32 + lg * 8];
      u32x4 p1 = *(const u32x4*)&sm.rb.Opk[oi][w][ks * 32 + lg * 8 + 4];
#pragma unroll
      for (int j = 0; j < 4; ++j) {
        Ah[ks][j] = (short)(p0[j] >> 16);     Al[ks][j] = (short)(p0[j] & 0xFFFFu);
        Ah[ks][j + 4] = (short)(p1[j] >> 16); Al[ks][j + 4] = (short)(p1[j] & 0xFFFFu);
      }
    }
    f32x4 acc[2];
#pragma unroll
    for (int nt = 0; nt < 2; ++nt)
#pragma unroll
      for (int r = 0; r < 4; ++r) acc[nt][r] = 0.f;
#pragma unroll
    for (int nt = 0; nt < 2; ++nt) {
      int ntg = chalf * 2 + nt;
#pragma unroll
      for (int ks = 0; ks < 2; ++ks) {
        const unsigned short* wp = WP + ((wm * 2 + 0) * 8 + (ntg * 2 + ks)) * 512 + lane * 8;
        bf16x8 Bh = *(const bf16x8*)wp;
        bf16x8 Bl = *(const bf16x8*)(wp + 4096);
        acc[nt] = mm3(Ah[ks], Al[ks], Bh, Bl, acc[nt]);
      }
    }
    float* og = out + (size_t)oi * 16777216u + xoff;
    const int w0 = stripe * 16 + lg * 4;
#pragma unroll
    for (int nt = 0; nt < 2; ++nt) {
      int c = (chalf * 2 + nt) * 16 + l15;
      u16x4 hv = *(const u16x4*)&sm.Xhi[oi][c][w0];
      u16x4 lv = *(const u16x4*)&sm.Xlo[oi][c][w0];
      f32x4 o;
#pragma unroll
      for (int r = 0; r < 4; ++r) o[r] = acc[nt][r] + comb(hv[r], lv[r]);
      *(f32x4*)(og + (size_t)c * 16384u + w0) = o;
    }
  }
}

extern "C" void kernel_launch(void* const* d_in, const int* in_sizes, int n_in,
                              void* d_out, int out_size, void* d_ws, size_t ws_size,
                              hipStream_t stream) {
  (void)in_sizes; (void)n_in; (void)out_size; (void)ws_size;
  unsigned short* WP = (unsigned short*)d_ws;                 // 65536 B
  float* vecs = (float*)((char*)d_ws + 65536);                // 1024 B
  scam_prepack<<<64, 256, 0, stream>>>(
      (const float*)d_in[2], (const float*)d_in[3],
      (const float*)d_in[4], (const float*)d_in[5],
      (const float*)d_in[6], (const float*)d_in[7],
      (const float*)d_in[8], (const float*)d_in[9], WP, vecs);
  scam_main<<<2048, 1024, 0, stream>>>(
      (const float*)d_in[0], (const float*)d_in[1], WP, vecs, (float*)d_out);
}

// Round 3
// 354.852 us; speedup vs baseline: 1.2609x; 1.0338x over previous
//
#include <hip/hip_runtime.h>
#include <cstdint>

// ---------------------------------------------------------------------------
// SCAM v3: fold Wq^T*Wk (+ LN affine algebra) into one prepacked matrix.
//   S2 = lam*S = r2[wk]*(T2@xh^T - m2[wk]*vT[wq]) + uT[wq],  E = exp2(S2)
//   T2 = LN1(xl) @ (g1*M*g2) with per-row epilogue, M = lam*Wq^T@Wk
//   O_h = (E@Xh)*zr  (row softmax),  O_l = (E^T@Xl)*zc  (col softmax)
//   xl_out^T = xl^T + Wv2@O_h^T ; xh_out^T = xh^T + Wv1@O_l^T
// LDS: X packed hi|lo u32 [c][w] pitch 130; T2/O bf16 planes pitch 72 (b128
// aligned reads); E packed u32 pitch 130. All fragment paths are b128/b64 or
// <=2-way-conflict scalar u32; softmax sums via shfl off C-fragments.
// ---------------------------------------------------------------------------

typedef __attribute__((ext_vector_type(8))) short bf16x8;
typedef __attribute__((ext_vector_type(4))) float f32x4;
typedef __attribute__((ext_vector_type(2))) unsigned u32x2;

#define LAM 0.18033688011112042f  // log2(e)/8

__device__ __forceinline__ unsigned rne_hi(float x) {
  unsigned u = __float_as_uint(x);
  return (u + 0x7FFFu + ((u >> 16) & 1u)) >> 16;
}
__device__ __forceinline__ void split2(float x, unsigned short& h, unsigned short& l) {
  unsigned hb = rne_hi(x);
  float rf = x - __uint_as_float(hb << 16);
  h = (unsigned short)hb;
  l = (unsigned short)(__float_as_uint(rf) >> 16);
}
__device__ __forceinline__ unsigned split_pack(float x) {
  unsigned short h, l; split2(x, h, l);
  return ((unsigned)h << 16) | (unsigned)l;
}
__device__ __forceinline__ float unpack_f(unsigned p) {
  return __uint_as_float(p & 0xFFFF0000u) + __uint_as_float(p << 16);
}
__device__ __forceinline__ f32x4 mm3(bf16x8 ah, bf16x8 al, bf16x8 bh, bf16x8 bl, f32x4 c) {
  c = __builtin_amdgcn_mfma_f32_16x16x32_bf16(al, bh, c, 0, 0, 0);
  c = __builtin_amdgcn_mfma_f32_16x16x32_bf16(ah, bl, c, 0, 0, 0);
  c = __builtin_amdgcn_mfma_f32_16x16x32_bf16(ah, bh, c, 0, 0, 0);
  return c;
}
__device__ __forceinline__ void row_frag(const unsigned* p, bf16x8& fh, bf16x8& fl) {
  u32x2 q0 = *(const u32x2*)p, q1 = *(const u32x2*)(p + 2);
  u32x2 q2 = *(const u32x2*)(p + 4), q3 = *(const u32x2*)(p + 6);
  unsigned w0 = q0[0], w1 = q0[1], w2 = q1[0], w3 = q1[1];
  unsigned w4 = q2[0], w5 = q2[1], w6 = q3[0], w7 = q3[1];
  fh[0] = (short)(w0 >> 16); fl[0] = (short)(w0 & 0xFFFFu);
  fh[1] = (short)(w1 >> 16); fl[1] = (short)(w1 & 0xFFFFu);
  fh[2] = (short)(w2 >> 16); fl[2] = (short)(w2 & 0xFFFFu);
  fh[3] = (short)(w3 >> 16); fl[3] = (short)(w3 & 0xFFFFu);
  fh[4] = (short)(w4 >> 16); fl[4] = (short)(w4 & 0xFFFFu);
  fh[5] = (short)(w5 >> 16); fl[5] = (short)(w5 & 0xFFFFu);
  fh[6] = (short)(w6 >> 16); fl[6] = (short)(w6 & 0xFFFFu);
  fh[7] = (short)(w7 >> 16); fl[7] = (short)(w7 & 0xFFFFu);
}

// ---------------- prepack: 16 blocks x 256 thr ------------------------------
// d_ws ushorts: [0,8192) = MB planes (B-frag layout), [8192,24576) = Wv1/Wv2
// A-frag planes. floats at byte 49152: [0:64) s1, [64:128) t1, [128:192) mbv,
// [192] smb, [193] tmb.  (s1/t1/smb/tmb accumulated via atomics; pre-zeroed.)
__global__ void scam_prepack(const float* __restrict__ ln1g, const float* __restrict__ ln1b,
                             const float* __restrict__ ln2g, const float* __restrict__ ln2b,
                             const float* __restrict__ Wq, const float* __restrict__ Wk,
                             const float* __restrict__ Wv1, const float* __restrict__ Wv2,
                             unsigned short* __restrict__ WP, float* __restrict__ vecs) {
  __shared__ float Wkl[64][65];
  __shared__ float wqc[64][4];
  __shared__ float gb[4][64];
  const int tid = threadIdx.x;
  const int blk = blockIdx.x;
  const int c0 = blk * 4;
#pragma unroll
  for (int i = 0; i < 16; ++i) {
    int idx = i * 256 + tid;
    Wkl[idx >> 6][idx & 63] = Wk[idx];
  }
  { int o = tid >> 2, ci = tid & 3; wqc[o][ci] = Wq[o * 64 + c0 + ci]; }
  { int g = tid >> 6, e = tid & 63;
    const float* src = (g == 0) ? ln1g : (g == 1) ? ln1b : (g == 2) ? ln2g : ln2b;
    gb[g][e] = src[e]; }
  __syncthreads();
  const int ci = tid >> 6, cp = tid & 63;
  const int c = c0 + ci;
  float d = 0.f;
#pragma unroll 8
  for (int o = 0; o < 64; ++o) d += wqc[o][ci] * Wkl[o][cp];
  d *= LAM;
  float mb = gb[0][c] * d * gb[2][cp];     // g1[c]*M'[c,cp]*g2[cp]
  float tb = gb[1][c] * d * gb[2][cp];     // b1[c]*M'[c,cp]*g2[cp]
  atomicAdd(&vecs[cp], mb);
  atomicAdd(&vecs[64 + cp], tb);
  {
    unsigned short h, l; split2(mb, h, l);
    int nt = cp >> 4, l15 = cp & 15, ks = c >> 5, lg = (c >> 3) & 3, j = c & 7;
    int ui = (nt * 2 + ks) * 512 + (lg * 16 + l15) * 8 + j;
    WP[ui] = h; WP[4096 + ui] = l;
  }
  // u[c] = sum_cp M'[c,cp]*b2[cp]  (wave-reduce over cp)
  float t = d * gb[3][cp];
#pragma unroll
  for (int s = 1; s < 64; s <<= 1) t += __shfl_xor(t, s);
  if ((tid & 63) == 0) {
    vecs[128 + c] = gb[0][c] * t;          // mbv
    atomicAdd(&vecs[192], gb[0][c] * t);   // smb
    atomicAdd(&vecs[193], gb[1][c] * t);   // tmb
  }
  // Wv A-frag prepack
  int idx2 = blk * 256 + tid;
#pragma unroll
  for (int m = 0; m < 2; ++m) {
    float v = (m ? Wv2 : Wv1)[idx2];
    unsigned short h, l; split2(v, h, l);
    int o = idx2 >> 6, cc = idx2 & 63;
    int mt = o >> 4, l15 = o & 15, ks = cc >> 5, lg = (cc >> 3) & 3, j = cc & 7;
    int ui = m * 8192 + (mt * 2 + ks) * 512 + (lg * 16 + l15) * 8 + j;
    WP[8192 + ui] = h;
    WP[8192 + ui + 4096] = l;
  }
}

// ---------------- main ------------------------------------------------------
struct SMem {
  unsigned X[2][64][130];                 // packed hi|lo, [mat][c][w]
  union {
    unsigned short T2[2][128][72];        // [plane][wq][c']
    unsigned E[128][130];                 // packed, [wq][wk]
    unsigned short O[2][2][128][72];      // [0=O_h,1=O_l][plane][w][c]
  } R;
  float m_[2][128], r_[2][128];
  float uT[128], vT[128], zr[128], zc[128];
  float vT2[2][128];                      // zero-region start (1536 floats)
  float zrP[2][128];
  float zcP[8][128];
  float s1v[64], t1v[64], mbv[64];
  float smbv, tmbv;
};

__launch_bounds__(1024, 1)
__global__ void scam_main(const float* __restrict__ xl_g, const float* __restrict__ xh_g,
                          const unsigned short* __restrict__ WP, const float* __restrict__ vecs,
                          float* __restrict__ out) {
  __shared__ __align__(16) SMem sm;
  const int tid = threadIdx.x;
  const int lane = tid & 63;
  const int wid = tid >> 6;
  const int stripe = wid >> 1, chalf = wid & 1;
  const int l15 = lane & 15, lg = lane >> 4;
  const int s = blockIdx.x;
  const size_t xoff = (size_t)(s >> 7) * 1048576u + (size_t)(s & 127) * 128u;

  // ---- load + init ----
  {
    float* Z = &sm.vT2[0][0];
    for (int i = tid; i < 1536; i += 1024) Z[i] = 0.f;
    if (tid < 64) {
      sm.s1v[tid] = vecs[tid];
      sm.t1v[tid] = vecs[64 + tid];
      sm.mbv[tid] = vecs[128 + tid];
    }
    if (tid == 64) { sm.smbv = vecs[192]; sm.tmbv = vecs[193]; }
    const int q = tid & 31, cb = tid >> 5;
#pragma unroll
    for (int i = 0; i < 4; ++i) {
      int mat = i >> 1, c = cb + (i & 1) * 32;
      const float* xg = mat ? xh_g : xl_g;
      f32x4 v = *(const f32x4*)(xg + xoff + (size_t)c * 16384u + q * 4);
      u32x2 p0, p1;
      p0[0] = split_pack(v[0]); p0[1] = split_pack(v[1]);
      p1[0] = split_pack(v[2]); p1[1] = split_pack(v[3]);
      *(u32x2*)&sm.X[mat][c][q * 4] = p0;
      *(u32x2*)&sm.X[mat][c][q * 4 + 2] = p1;
    }
  }
  __syncthreads();

  // ---- LN stats (+ s3 = xl . mbv for uT) ----
  {
    const int row = tid >> 2, qu = tid & 3;
    const int mat = row >> 7, w = row & 127;
    float a1 = 0.f, a2 = 0.f, a3 = 0.f;
#pragma unroll
    for (int i = 0; i < 16; ++i) {
      int c = qu + i * 4;
      float x = unpack_f(sm.X[mat][c][w]);
      a1 += x; a2 += x * x;
      if (mat == 0) a3 += x * sm.mbv[c];
    }
    a1 += __shfl_xor(a1, 1); a2 += __shfl_xor(a2, 1); a3 += __shfl_xor(a3, 1);
    a1 += __shfl_xor(a1, 2); a2 += __shfl_xor(a2, 2); a3 += __shfl_xor(a3, 2);
    if (qu == 0) {
      float mn = a1 * (1.f / 64.f);
      float var = fmaxf(a2 * (1.f / 64.f) - mn * mn, 0.f);
      float rs = rsqrtf(var + 1e-5f);
      sm.m_[mat][w] = mn; sm.r_[mat][w] = rs;
      if (mat == 0) sm.uT[w] = rs * (a3 - mn * sm.smbv) + sm.tmbv;
    }
  }
  __syncthreads();

  // ---- G1: T2 = LN1(xl) @ MB  (LN in epilogue) ----
  {
    const int wA = stripe * 16 + l15;
    bf16x8 Ah[2], Al[2];
#pragma unroll
    for (int ks = 0; ks < 2; ++ks)
#pragma unroll
      for (int j = 0; j < 8; ++j) {
        unsigned p = sm.X[0][ks * 32 + lg * 8 + j][wA];
        Ah[ks][j] = (short)(p >> 16); Al[ks][j] = (short)(p & 0xFFFFu);
      }
    f32x4 acc[2];
#pragma unroll
    for (int nt = 0; nt < 2; ++nt)
#pragma unroll
      for (int r = 0; r < 4; ++r) acc[nt][r] = 0.f;
#pragma unroll
    for (int nt = 0; nt < 2; ++nt) {
      int ntg = chalf * 2 + nt;
#pragma unroll
      for (int ks = 0; ks < 2; ++ks) {
        const unsigned short* wp = WP + (ntg * 2 + ks) * 512 + lane * 8;
        bf16x8 Bh = *(const bf16x8*)wp;
        bf16x8 Bl = *(const bf16x8*)(wp + 4096);
        acc[nt] = mm3(Ah[ks], Al[ks], Bh, Bl, acc[nt]);
      }
    }
    float vsum[4] = {0.f, 0.f, 0.f, 0.f};
#pragma unroll
    for (int nt = 0; nt < 2; ++nt) {
      int cp = (chalf * 2 + nt) * 16 + l15;
      float sv = sm.s1v[cp], tv = sm.t1v[cp];
#pragma unroll
      for (int r = 0; r < 4; ++r) {
        int wr = stripe * 16 + lg * 4 + r;
        float t2 = sm.r_[0][wr] * (acc[nt][r] - sm.m_[0][wr] * sv) + tv;
        unsigned short h, l; split2(t2, h, l);
        sm.R.T2[0][wr][cp] = h; sm.R.T2[1][wr][cp] = l;
        vsum[r] += t2;
      }
    }
#pragma unroll
    for (int r = 0; r < 4; ++r) {
      float v = vsum[r];
      v += __shfl_xor(v, 1); v += __shfl_xor(v, 2);
      v += __shfl_xor(v, 4); v += __shfl_xor(v, 8);
      if (l15 == 0) sm.vT2[chalf][stripe * 16 + lg * 4 + r] = v;
    }
  }
  __syncthreads();

  // ---- G2: S2 = T2 @ xh^T (epilogue affine) -> E = exp2(S2) ----
  {
    if (tid < 128) sm.vT[tid] = sm.vT2[0][tid] + sm.vT2[1][tid];
    const int wA = stripe * 16 + l15;
    bf16x8 Ah[2], Al[2];
#pragma unroll
    for (int ks = 0; ks < 2; ++ks) {
      Ah[ks] = *(const bf16x8*)&sm.R.T2[0][wA][ks * 32 + lg * 8];
      Al[ks] = *(const bf16x8*)&sm.R.T2[1][wA][ks * 32 + lg * 8];
    }
    f32x4 acc[4];
#pragma unroll
    for (int nt = 0; nt < 4; ++nt)
#pragma unroll
      for (int r = 0; r < 4; ++r) acc[nt][r] = 0.f;
#pragma unroll
    for (int nt = 0; nt < 4; ++nt) {
      int wk = (chalf * 4 + nt) * 16 + l15;
#pragma unroll
      for (int ks = 0; ks < 2; ++ks) {
        bf16x8 Bh, Bl;
#pragma unroll
        for (int j = 0; j < 8; ++j) {
          unsigned p = sm.X[1][ks * 32 + lg * 8 + j][wk];
          Bh[j] = (short)(p >> 16); Bl[j] = (short)(p & 0xFFFFu);
        }
        acc[nt] = mm3(Ah[ks], Al[ks], Bh, Bl, acc[nt]);
      }
    }
    __syncthreads();   // T2 reads done; vT ready; E may overwrite T2
    float ev[4][4];
#pragma unroll
    for (int nt = 0; nt < 4; ++nt) {
      int wk = (chalf * 4 + nt) * 16 + l15;
      float rr = sm.r_[1][wk], mm = sm.m_[1][wk];
#pragma unroll
      for (int r = 0; r < 4; ++r) {
        int wq = stripe * 16 + lg * 4 + r;
        float s2 = rr * (acc[nt][r] - mm * sm.vT[wq]) + sm.uT[wq];
        float e = __builtin_amdgcn_exp2f(s2);
        ev[nt][r] = e;
        sm.R.E[wq][wk] = split_pack(e);
      }
    }
#pragma unroll
    for (int r = 0; r < 4; ++r) {
      float v = ev[0][r] + ev[1][r] + ev[2][r] + ev[3][r];
      v += __shfl_xor(v, 1); v += __shfl_xor(v, 2);
      v += __shfl_xor(v, 4); v += __shfl_xor(v, 8);
      if (l15 == 0) sm.zrP[chalf][stripe * 16 + lg * 4 + r] = v;
    }
#pragma unroll
    for (int nt = 0; nt < 4; ++nt) {
      float v = ev[nt][0] + ev[nt][1] + ev[nt][2] + ev[nt][3];
      v += __shfl_xor(v, 16); v += __shfl_xor(v, 32);
      if (lg == 0) sm.zcP[stripe][(chalf * 4 + nt) * 16 + l15] = v;
    }
  }
  __syncthreads();

  // ---- PV: O_h = (E@Xh)*zr ; O_l = (E^T@Xl)*zc ----
  {
    if (tid < 128) {
      sm.zr[tid] = 1.0f / (sm.zrP[0][tid] + sm.zrP[1][tid]);
    } else if (tid < 256) {
      int c = tid - 128;
      float t = 0.f;
#pragma unroll
      for (int st = 0; st < 8; ++st) t += sm.zcP[st][c];
      sm.zc[c] = 1.0f / t;
    }
    const int wA = stripe * 16 + l15;
    f32x4 aH[2], aL[2];
#pragma unroll
    for (int nt = 0; nt < 2; ++nt)
#pragma unroll
      for (int r = 0; r < 4; ++r) { aH[nt][r] = 0.f; aL[nt][r] = 0.f; }
#pragma unroll
    for (int kt = 0; kt < 4; ++kt) {
      bf16x8 Eh, El;
      row_frag(&sm.R.E[wA][kt * 32 + lg * 8], Eh, El);
      bf16x8 Th, Tl;
#pragma unroll
      for (int j = 0; j < 8; ++j) {
        unsigned p = sm.R.E[kt * 32 + lg * 8 + j][wA];
        Th[j] = (short)(p >> 16); Tl[j] = (short)(p & 0xFFFFu);
      }
#pragma unroll
      for (int nt = 0; nt < 2; ++nt) {
        int c = (chalf * 2 + nt) * 16 + l15;
        bf16x8 BHh, BHl, BLh, BLl;
        row_frag(&sm.X[1][c][kt * 32 + lg * 8], BHh, BHl);
        row_frag(&sm.X[0][c][kt * 32 + lg * 8], BLh, BLl);
        aH[nt] = mm3(Eh, El, BHh, BHl, aH[nt]);
        aL[nt] = mm3(Th, Tl, BLh, BLl, aL[nt]);
      }
    }
    __syncthreads();   // E reads done; zr/zc ready; O may overwrite E
#pragma unroll
    for (int nt = 0; nt < 2; ++nt) {
      int c = (chalf * 2 + nt) * 16 + l15;
#pragma unroll
      for (int r = 0; r < 4; ++r) {
        int w = stripe * 16 + lg * 4 + r;
        unsigned short h, l;
        split2(aH[nt][r] * sm.zr[w], h, l);
        sm.R.O[0][0][w][c] = h; sm.R.O[0][1][w][c] = l;
        split2(aL[nt][r] * sm.zc[w], h, l);
        sm.R.O[1][0][w][c] = h; sm.R.O[1][1][w][c] = l;
      }
    }
  }
  __syncthreads();

  // ---- P7: out_l^T = xl^T + Wv2@O_h^T ; out_h^T = xh^T + Wv1@O_l^T ----
  {
    const int mt = wid >> 2, np = wid & 3;
#pragma unroll
    for (int oi = 0; oi < 2; ++oi) {
      const int osel = oi;               // 0 -> O_h, 1 -> O_l
      const int wsel = oi ? 0 : 1;       // 0 -> Wv1, 1 -> Wv2
      const unsigned short* WA = WP + 8192 + wsel * 8192;
      bf16x8 Ah[2], Al[2];
#pragma unroll
      for (int ks = 0; ks < 2; ++ks) {
        const unsigned short* wp = WA + (mt * 2 + ks) * 512 + lane * 8;
        Ah[ks] = *(const bf16x8*)wp;
        Al[ks] = *(const bf16x8*)(wp + 4096);
      }
      f32x4 acc[2];
#pragma unroll
      for (int nt2 = 0; nt2 < 2; ++nt2)
#pragma unroll
        for (int r = 0; r < 4; ++r) acc[nt2][r] = 0.f;
#pragma unroll
      for (int nt2 = 0; nt2 < 2; ++nt2) {
        int wc = (np * 2 + nt2) * 16 + l15;
#pragma unroll
        for (int ks = 0; ks < 2; ++ks) {
          bf16x8 Bh = *(const bf16x8*)&sm.R.O[osel][0][wc][ks * 32 + lg * 8];
          bf16x8 Bl = *(const bf16x8*)&sm.R.O[osel][1][wc][ks * 32 + lg * 8];
          acc[nt2] = mm3(Ah[ks], Al[ks], Bh, Bl, acc[nt2]);
        }
      }
      const float* res = (oi ? xh_g : xl_g) + xoff;
      float* og = out + (size_t)oi * 16777216u + xoff;
#pragma unroll
      for (int nt2 = 0; nt2 < 2; ++nt2) {
        int wc = (np * 2 + nt2) * 16 + l15;
#pragma unroll
        for (int r = 0; r < 4; ++r) {
          int o = mt * 16 + lg * 4 + r;
          size_t a = (size_t)o * 16384u + wc;
          og[a] = acc[nt2][r] + res[a];
        }
      }
    }
  }
}

extern "C" void kernel_launch(void* const* d_in, const int* in_sizes, int n_in,
                              void* d_out, int out_size, void* d_ws, size_t ws_size,
                              hipStream_t stream) {
  (void)in_sizes; (void)n_in; (void)out_size; (void)ws_size;
  unsigned short* WP = (unsigned short*)d_ws;            // 48 KiB frag planes
  float* vecs = (float*)((char*)d_ws + 49152);           // 256 floats
  hipMemsetAsync(vecs, 0, 1024, stream);
  scam_prepack<<<16, 256, 0, stream>>>(
      (const float*)d_in[2], (const float*)d_in[3],
      (const float*)d_in[4], (const float*)d_in[5],
      (const float*)d_in[6], (const float*)d_in[7],
      (const float*)d_in[8], (const float*)d_in[9], WP, vecs);
  scam_main<<<2048, 1024, 0, stream>>>(
      (const float*)d_in[0], (const float*)d_in[1], WP, vecs, (float*)d_out);
}